// Round 4
// baseline (196.160 us; speedup 1.0000x reference)
//
#include <hip/hip_runtime.h>
#include <hip/hip_fp16.h>
#include <math.h>

// Problem constants: N=500, DEG=16, E=8000, B=8, T=12 (BT=96), H=64, F=32
#define N_NODES 500
#define DEG     16
#define E_EDGES 8000
#define BT      96
#define H_      64
#define F_      32
#define ROWS    (BT * N_NODES)   // 48000 rows, r = bt*500 + n

__device__ __forceinline__ float sigmoidf_(float x) {
    return 1.0f / (1.0f + __expf(-x));
}

// ---------------------------------------------------------------------------
// Kernel P: transpose weight planes -> wT[c][jj][h] (6*64*64 floats)
// plane c: 0=A_U 1=B_U 2=C_U 3=A_V 4=B_V 5=C_V; A=W3[0].view(128,64),
// B=W3[1], C=b3; U rows 0..63, V rows 64..127.
// ---------------------------------------------------------------------------
__global__ __launch_bounds__(256) void wt_prep_kernel(
        const float* __restrict__ W3, const float* __restrict__ b3,
        float* __restrict__ wT) {
    int i = blockIdx.x * 256 + threadIdx.x;
    if (i >= 6 * 64 * 64) return;
    int c  = i >> 12;
    int jj = (i >> 6) & 63;
    int h  = i & 63;
    const float* plane = (c % 3 == 0) ? W3 : (c % 3 == 1) ? (W3 + 8192) : b3;
    int rowbase = (c < 3) ? 0 : 64;
    wT[i] = plane[(rowbase + h) * 64 + jj];
}

// ---------------------------------------------------------------------------
// Kernel A: per-edge hypernetwork  h = sig(sig(feat@W1+b1)@W2+b2) -> h0,h1
// ---------------------------------------------------------------------------
__global__ __launch_bounds__(256) void hyper_kernel(
        const float* __restrict__ feature, const float* __restrict__ dist,
        const float* __restrict__ W1, const float* __restrict__ b1,
        const float* __restrict__ W2, const float* __restrict__ b2,
        const int* __restrict__ src, const int* __restrict__ dst,
        float* __restrict__ hbuf) {
    __shared__ float sW1[65 * 16];
    __shared__ float sb1[16];
    __shared__ float sW2[32];
    __shared__ float sb2[2];
    for (int i = threadIdx.x; i < 65 * 16; i += blockDim.x) sW1[i] = W1[i];
    if (threadIdx.x < 16) sb1[threadIdx.x] = b1[threadIdx.x];
    if (threadIdx.x < 32) sW2[threadIdx.x] = W2[threadIdx.x];
    if (threadIdx.x < 2)  sb2[threadIdx.x] = b2[threadIdx.x];
    __syncthreads();

    int e = blockIdx.x * blockDim.x + threadIdx.x;
    if (e >= E_EDGES) return;
    int s = src[e], d = dst[e];
    float fs[F_], fd[F_];
    #pragma unroll
    for (int f = 0; f < F_; f++) fs[f] = feature[s * F_ + f];
    #pragma unroll
    for (int f = 0; f < F_; f++) fd[f] = feature[d * F_ + f];
    float dv = dist[e];

    float h1v[16];
    #pragma unroll
    for (int m = 0; m < 16; m++) {
        float acc = sb1[m] + dv * sW1[64 * 16 + m];
        #pragma unroll
        for (int f = 0; f < F_; f++) acc += fs[f] * sW1[f * 16 + m];
        #pragma unroll
        for (int f = 0; f < F_; f++) acc += fd[f] * sW1[(F_ + f) * 16 + m];
        h1v[m] = sigmoidf_(acc);
    }
    float o0 = sb2[0], o1 = sb2[1];
    #pragma unroll
    for (int m = 0; m < 16; m++) {
        o0 += h1v[m] * sW2[m * 2 + 0];
        o1 += h1v[m] * sW2[m * 2 + 1];
    }
    hbuf[e * 2 + 0] = sigmoidf_(o0);
    hbuf[e * 2 + 1] = sigmoidf_(o1);
}

// ---------------------------------------------------------------------------
// Kernel B: flat GEMM [48000,64] @ [64,384], fp16 half4 outputs (bt-major):
//   UpackH[r][jj] = half4{ uA, uB, uC, state[r][jj] }  (one 8B store)
//   VpackH[r][jj] = half4{ vA, vB, vC, 0 }
// 256 threads = 4 waves: jj = tid&63, group g = (tid>>6)&1 (U/V planes),
// rowhalf rh = tid>>7. Each thread holds 3 weight columns (48 float4 = 192
// VGPRs) and sweeps 48 rows via wave-uniform LDS broadcasts.
// amdgpu_waves_per_eu(2,2): pin 2 waves/SIMD -> 256-VGPR budget, so the
// allocator keeps the weight arrays in VGPRs (R3's launch_bounds(.,1) left
// the occupancy target free and it demoted the weights -> 2.25x VALU).
// ---------------------------------------------------------------------------
__global__ __launch_bounds__(256)
__attribute__((amdgpu_waves_per_eu(2, 2)))
void gemm_pack_kernel(
        const float* __restrict__ state,
        const float* __restrict__ wT,
        float2* __restrict__ UpackH, float2* __restrict__ VpackH) {
    int tid = threadIdx.x;
    int jj = tid & 63;
    int g  = (tid >> 6) & 1;
    int rh = tid >> 7;
    int r0 = blockIdx.x * BT;

    __shared__ __align__(16) float s_tile[BT][H_];   // 24 KB

    const float4* st4 = (const float4*)state;
    float4* ls4 = (float4*)&s_tile[0][0];
    #pragma unroll
    for (int i = 0; i < 6; i++)
        ls4[tid + 256 * i] = st4[(size_t)r0 * 16 + tid + 256 * i];

    // 3 weight columns for this thread's plane group, 16 float4 each
    const float4* wtA = (const float4*)(wT + ((3 * g + 0) * 64 + jj) * 64);
    const float4* wtB = (const float4*)(wT + ((3 * g + 1) * 64 + jj) * 64);
    const float4* wtC = (const float4*)(wT + ((3 * g + 2) * 64 + jj) * 64);
    float4 wA[16], wB[16], wC[16];
    #pragma unroll
    for (int k = 0; k < 16; k++) wA[k] = wtA[k];
    #pragma unroll
    for (int k = 0; k < 16; k++) wB[k] = wtB[k];
    #pragma unroll
    for (int k = 0; k < 16; k++) wC[k] = wtC[k];

    __syncthreads();

    float2* outp = g ? VpackH : UpackH;

    for (int rr = 0; rr < 48; rr++) {
        int row = rh * 48 + rr;
        const float4* srow = (const float4*)&s_tile[row][0];
        float aA = 0.0f, aB = 0.0f, aC = 0.0f;
        #pragma unroll
        for (int k = 0; k < 16; k++) {
            float4 sv = srow[k];   // wave-uniform -> LDS broadcast
            aA += sv.x * wA[k].x; aA += sv.y * wA[k].y;
            aA += sv.z * wA[k].z; aA += sv.w * wA[k].w;
            aB += sv.x * wB[k].x; aB += sv.y * wB[k].y;
            aB += sv.z * wB[k].z; aB += sv.w * wB[k].w;
            aC += sv.x * wC[k].x; aC += sv.y * wC[k].y;
            aC += sv.z * wC[k].z; aC += sv.w * wC[k].w;
        }
        float w4 = g ? 0.0f : s_tile[row][jj];
        __half2 lo = __halves2half2(__float2half(aA), __float2half(aB));
        __half2 hi = __halves2half2(__float2half(aC), __float2half(w4));
        float2 pack;
        *(__half2*)&pack.x = lo;
        *(__half2*)&pack.y = hi;
        outp[(size_t)(r0 + row) * H_ + jj] = pack;
    }
}

// ---------------------------------------------------------------------------
// Kernel C: segment softmax, single-pass (no running-max: post-leaky alpha
// is bounded ~[-0.5, 50], exp() cannot overflow fp32; softmax is
// shift-invariant so this matches the reference).
// Grid order g-FASTEST: bt = blockIdx/125, g = blockIdx%125 -> the ~256
// concurrently-resident blocks span only ~2 bt-slices; per-XCD gather
// working set ~2 x 256 KB, L2-resident under any XCD mapping (R3's
// bt-fastest order spanned all 96 slices -> 24 MB -> L3-bound).
// ---------------------------------------------------------------------------
__global__ __launch_bounds__(256) void combine_kernel(
        const float2* __restrict__ Upack,   // half4 as float2
        const float2* __restrict__ Vpack,
        const float* __restrict__ hbuf, const int* __restrict__ src,
        const float* __restrict__ gate,
        float* __restrict__ out) {
    int bt = blockIdx.x / 125;
    int g  = blockIdx.x % 125;
    int tid = threadIdx.x;
    int jj  = tid & 63;
    int sub = tid >> 6;             // 0..3
    int n   = g * 4 + sub;
    int n0  = g * 4;

    __shared__ int   s_src[64];
    __shared__ float s_h0[64], s_h1[64];
    if (tid < 64) {
        int e = n0 * DEG + tid;     // edges of nodes n0..n0+3 contiguous
        s_src[tid] = src[e];
        s_h0[tid]  = hbuf[e * 2 + 0];
        s_h1[tid]  = hbuf[e * 2 + 1];
    }
    __syncthreads();

    float sg = sigmoidf_(gate[0]);

    size_t vidx = ((size_t)bt * N_NODES + n) * H_ + jj;
    float2 vraw = Vpack[vidx];
    float2 v01 = __half22float2(*(const __half2*)&vraw.x);
    float2 v23 = __half22float2(*(const __half2*)&vraw.y);
    float va = v01.x, vb = v01.y, vc = v23.x;

    size_t btbase = (size_t)bt * N_NODES * H_;
    float l = 0.0f, num = 0.0f;
    #pragma unroll
    for (int e = 0; e < DEG; e++) {
        int ed = sub * DEG + e;
        int se = s_src[ed];
        float h0 = s_h0[ed], h1 = s_h1[ed];
        float2 uraw = Upack[btbase + (size_t)se * H_ + jj];
        float2 u01 = __half22float2(*(const __half2*)&uraw.x);
        float2 u23 = __half22float2(*(const __half2*)&uraw.y);
        float a = h0 * (u01.x + va) + h1 * (u01.y + vb) + (u23.x + vc);
        a = (a > 0.0f) ? a : 0.01f * a;               // leaky_relu 0.01
        float p = __expf(a);
        l   += p;
        num += p * u23.y;
    }
    float r = fmaxf(num / l, 0.0f) * sg;
    out[vidx] = r;   // [bt][n][jj] == [B,T,N,H]
}

// ---------------------------------------------------------------------------
// Workspace layout (bytes):
//   [0, 64000)                  hbuf   (E*2 floats)
//   [131072, +98304)            wT     (6*64*64 floats)
//   [262144, +24576000)         UpackH (48000*64 half4)
//   [25165824, +24576000)       VpackH            total ~47.5 MB
// ---------------------------------------------------------------------------
extern "C" void kernel_launch(void* const* d_in, const int* in_sizes, int n_in,
                              void* d_out, int out_size, void* d_ws, size_t ws_size,
                              hipStream_t stream) {
    const float* state   = (const float*)d_in[0];
    const float* feature = (const float*)d_in[1];
    const float* dist    = (const float*)d_in[2];
    const float* W1      = (const float*)d_in[3];
    const float* b1      = (const float*)d_in[4];
    const float* W2      = (const float*)d_in[5];
    const float* b2      = (const float*)d_in[6];
    const float* W3      = (const float*)d_in[7];
    const float* b3      = (const float*)d_in[8];
    const float* gate    = (const float*)d_in[9];
    const int*   src     = (const int*)d_in[10];
    const int*   dst     = (const int*)d_in[11];
    float* out = (float*)d_out;

    char* ws = (char*)d_ws;
    float*  hbuf   = (float*)(ws);
    float*  wT     = (float*)(ws + 131072ULL);
    float2* UpackH = (float2*)(ws + 262144ULL);
    float2* VpackH = (float2*)(ws + 25165824ULL);

    hipLaunchKernelGGL(wt_prep_kernel, dim3((6 * 64 * 64 + 255) / 256), dim3(256), 0, stream,
                       W3, b3, wT);
    hipLaunchKernelGGL(hyper_kernel, dim3((E_EDGES + 255) / 256), dim3(256), 0, stream,
                       feature, dist, W1, b1, W2, b2, src, dst, hbuf);
    hipLaunchKernelGGL(gemm_pack_kernel, dim3(ROWS / BT), dim3(256), 0, stream,
                       state, wT, UpackH, VpackH);
    hipLaunchKernelGGL(combine_kernel, dim3(125 * BT), dim3(256), 0, stream,
                       (const float2*)UpackH, (const float2*)VpackH, hbuf, src, gate, out);
}

// Round 5
// 141.260 us; speedup vs baseline: 1.3886x; 1.3886x over previous
//
#include <hip/hip_runtime.h>
#include <hip/hip_fp16.h>
#include <math.h>

// Problem constants: N=500, DEG=16, E=8000, B=8, T=12 (BT=96), H=64, F=32
#define N_NODES 500
#define DEG     16
#define E_EDGES 8000
#define BT      96
#define H_      64
#define F_      32
#define ROWS    (BT * N_NODES)   // 48000 rows, r = bt*500 + n
#define SROW    72               // padded LDS row stride in halves (144 B = 9*16)

typedef _Float16 f16;
typedef f16   half8v  __attribute__((ext_vector_type(8)));
typedef f16   half4v  __attribute__((ext_vector_type(4)));
typedef float f32x4v  __attribute__((ext_vector_type(4)));

__device__ __forceinline__ float sigmoidf_(float x) {
    return 1.0f / (1.0f + __expf(-x));
}

// ---------------------------------------------------------------------------
// Kernel P: weight planes -> wTh[c][jj][h] fp16 (6*64*64), [col][k] layout.
// plane c: 0=A_U 1=B_U 2=C_U 3=A_V 4=B_V 5=C_V; A=W3[0].view(128,64),
// B=W3[1], C=b3; U rows (k) 0..63, V rows 64..127.
// ---------------------------------------------------------------------------
__global__ __launch_bounds__(256) void wt_prep_kernel(
        const float* __restrict__ W3, const float* __restrict__ b3,
        f16* __restrict__ wTh) {
    int i = blockIdx.x * 256 + threadIdx.x;
    if (i >= 6 * 64 * 64) return;
    int c  = i >> 12;
    int jj = (i >> 6) & 63;
    int h  = i & 63;
    const float* plane = (c % 3 == 0) ? W3 : (c % 3 == 1) ? (W3 + 8192) : b3;
    int rowbase = (c < 3) ? 0 : 64;
    wTh[i] = (f16)plane[(rowbase + h) * 64 + jj];
}

// ---------------------------------------------------------------------------
// Kernel A: per-edge hypernetwork  h = sig(sig(feat@W1+b1)@W2+b2) -> h0,h1
// ---------------------------------------------------------------------------
__global__ __launch_bounds__(256) void hyper_kernel(
        const float* __restrict__ feature, const float* __restrict__ dist,
        const float* __restrict__ W1, const float* __restrict__ b1,
        const float* __restrict__ W2, const float* __restrict__ b2,
        const int* __restrict__ src, const int* __restrict__ dst,
        float* __restrict__ hbuf) {
    __shared__ float sW1[65 * 16];
    __shared__ float sb1[16];
    __shared__ float sW2[32];
    __shared__ float sb2[2];
    for (int i = threadIdx.x; i < 65 * 16; i += blockDim.x) sW1[i] = W1[i];
    if (threadIdx.x < 16) sb1[threadIdx.x] = b1[threadIdx.x];
    if (threadIdx.x < 32) sW2[threadIdx.x] = W2[threadIdx.x];
    if (threadIdx.x < 2)  sb2[threadIdx.x] = b2[threadIdx.x];
    __syncthreads();

    int e = blockIdx.x * blockDim.x + threadIdx.x;
    if (e >= E_EDGES) return;
    int s = src[e], d = dst[e];
    float fs[F_], fd[F_];
    #pragma unroll
    for (int f = 0; f < F_; f++) fs[f] = feature[s * F_ + f];
    #pragma unroll
    for (int f = 0; f < F_; f++) fd[f] = feature[d * F_ + f];
    float dv = dist[e];

    float h1v[16];
    #pragma unroll
    for (int m = 0; m < 16; m++) {
        float acc = sb1[m] + dv * sW1[64 * 16 + m];
        #pragma unroll
        for (int f = 0; f < F_; f++) acc += fs[f] * sW1[f * 16 + m];
        #pragma unroll
        for (int f = 0; f < F_; f++) acc += fd[f] * sW1[(F_ + f) * 16 + m];
        h1v[m] = sigmoidf_(acc);
    }
    float o0 = sb2[0], o1 = sb2[1];
    #pragma unroll
    for (int m = 0; m < 16; m++) {
        o0 += h1v[m] * sW2[m * 2 + 0];
        o1 += h1v[m] * sW2[m * 2 + 1];
    }
    hbuf[e * 2 + 0] = sigmoidf_(o0);
    hbuf[e * 2 + 1] = sigmoidf_(o1);
}

// ---------------------------------------------------------------------------
// Kernel B (MFMA): flat GEMM [48000,64] @ [64,384] via mfma_f32_16x16x32_f16.
// Block = 256 thr = 4 waves, 64 rows/block (750 blocks).
// LDS: sW[384][72] fp16 (full weight, [col][k]) + sS[64][72] fp16 (S tile).
// Row stride 72 halves = 144 B: 16B-aligned (9*16) and 2-way-conflict max.
// Wave w owns rows m0=w*16; for q=0..3, computes all 6 plane tiles
// (2 MFMAs each, K=64) and packs {uA,uB,uC,state} / {vA,vB,vC,0} as half4
// using the C-layout col=lane&15, row=quad*4+reg. MFMA pipe finally used;
// kernel is pure data movement otherwise (R2-R4: fp32 VALU GEMM stuck at
// 64-76 us, allocator refused register-resident weights 3 rounds running).
// ---------------------------------------------------------------------------
__global__ __launch_bounds__(256) void gemm_pack_mfma(
        const float* __restrict__ state,
        const f16* __restrict__ wTh,
        half4v* __restrict__ UpackH, half4v* __restrict__ VpackH) {
    __shared__ __align__(16) f16 sW[384 * SROW];   // 55.3 KB
    __shared__ __align__(16) f16 sS[64 * SROW];    //  9.2 KB
    int tid = threadIdx.x;
    int r0  = blockIdx.x * 64;

    // stage W: 384 rows x 64 halves (8 x 16B chunks per row)
    #pragma unroll
    for (int i = 0; i < 12; i++) {
        int idx = tid + 256 * i;           // 3072 chunks
        int cc = idx >> 3, p = idx & 7;
        *(float4*)&sW[cc * SROW + p * 8] = ((const float4*)wTh)[idx];
    }
    // stage S: 64 rows x 64 fp32 -> fp16
    #pragma unroll
    for (int i = 0; i < 4; i++) {
        int f4 = tid + 256 * i;            // 1024 float4
        int row = f4 >> 4, p = f4 & 15;
        float4 v = ((const float4*)state)[(size_t)(r0 + row) * 16 + p];
        half4v hv = { (f16)v.x, (f16)v.y, (f16)v.z, (f16)v.w };
        *(half4v*)&sS[row * SROW + p * 4] = hv;
    }
    __syncthreads();

    int wv   = tid >> 6;
    int lane = tid & 63;
    int col  = lane & 15;
    int quad = lane >> 4;
    int m0   = wv * 16;

    // A fragments (shared across all column tiles): k = kc*32 + quad*8 + j
    half8v a0 = *(const half8v*)&sS[(m0 + col) * SROW + quad * 8];
    half8v a1 = *(const half8v*)&sS[(m0 + col) * SROW + 32 + quad * 8];

    #pragma unroll
    for (int q = 0; q < 4; q++) {
        f32x4v acc[6];
        #pragma unroll
        for (int pl = 0; pl < 6; pl++) {
            int cc0 = pl * 64 + q * 16;
            half8v b0 = *(const half8v*)&sW[(cc0 + col) * SROW + quad * 8];
            half8v b1 = *(const half8v*)&sW[(cc0 + col) * SROW + 32 + quad * 8];
            f32x4v a = {0.0f, 0.0f, 0.0f, 0.0f};
            a = __builtin_amdgcn_mfma_f32_16x16x32_f16(a0, b0, a, 0, 0, 0);
            a = __builtin_amdgcn_mfma_f32_16x16x32_f16(a1, b1, a, 0, 0, 0);
            acc[pl] = a;
        }
        f16 sv[4];
        #pragma unroll
        for (int r = 0; r < 4; r++)
            sv[r] = sS[(m0 + quad * 4 + r) * SROW + q * 16 + col];
        #pragma unroll
        for (int r = 0; r < 4; r++) {
            size_t row = (size_t)(r0 + m0 + quad * 4 + r);
            int jj = q * 16 + col;
            half4v up = { (f16)acc[0][r], (f16)acc[1][r], (f16)acc[2][r], sv[r] };
            half4v vp = { (f16)acc[3][r], (f16)acc[4][r], (f16)acc[5][r], (f16)0.0f };
            UpackH[row * H_ + jj] = up;
            VpackH[row * H_ + jj] = vp;
        }
    }
}

// ---------------------------------------------------------------------------
// Kernel C: segment softmax, single-pass (post-leaky alpha bounded; exp
// can't overflow fp32; softmax shift-invariant). Grid g-fastest:
// bt = blockIdx/125 -> the ~resident blocks span ~2 bt-slices; per-XCD
// gather set ~512 KB, L2-resident.
// ---------------------------------------------------------------------------
__global__ __launch_bounds__(256) void combine_kernel(
        const float2* __restrict__ Upack,   // half4 as float2
        const float2* __restrict__ Vpack,
        const float* __restrict__ hbuf, const int* __restrict__ src,
        const float* __restrict__ gate,
        float* __restrict__ out) {
    int bt = blockIdx.x / 125;
    int g  = blockIdx.x % 125;
    int tid = threadIdx.x;
    int jj  = tid & 63;
    int sub = tid >> 6;             // 0..3
    int n   = g * 4 + sub;
    int n0  = g * 4;

    __shared__ int   s_src[64];
    __shared__ float s_h0[64], s_h1[64];
    if (tid < 64) {
        int e = n0 * DEG + tid;     // edges of nodes n0..n0+3 contiguous
        s_src[tid] = src[e];
        s_h0[tid]  = hbuf[e * 2 + 0];
        s_h1[tid]  = hbuf[e * 2 + 1];
    }
    __syncthreads();

    float sg = sigmoidf_(gate[0]);

    size_t vidx = ((size_t)bt * N_NODES + n) * H_ + jj;
    float2 vraw = Vpack[vidx];
    float2 v01 = __half22float2(*(const __half2*)&vraw.x);
    float2 v23 = __half22float2(*(const __half2*)&vraw.y);
    float va = v01.x, vb = v01.y, vc = v23.x;

    size_t btbase = (size_t)bt * N_NODES * H_;
    float l = 0.0f, num = 0.0f;
    #pragma unroll
    for (int e = 0; e < DEG; e++) {
        int ed = sub * DEG + e;
        int se = s_src[ed];
        float h0 = s_h0[ed], h1 = s_h1[ed];
        float2 uraw = Upack[btbase + (size_t)se * H_ + jj];
        float2 u01 = __half22float2(*(const __half2*)&uraw.x);
        float2 u23 = __half22float2(*(const __half2*)&uraw.y);
        float a = h0 * (u01.x + va) + h1 * (u01.y + vb) + (u23.x + vc);
        a = (a > 0.0f) ? a : 0.01f * a;               // leaky_relu 0.01
        float p = __expf(a);
        l   += p;
        num += p * u23.y;
    }
    float r = fmaxf(num / l, 0.0f) * sg;
    out[vidx] = r;   // [bt][n][jj] == [B,T,N,H]
}

// ---------------------------------------------------------------------------
// Workspace layout (bytes):
//   [0, 64000)                  hbuf   (E*2 floats)
//   [131072, +49152)            wTh    (6*64*64 fp16)
//   [262144, +24576000)         UpackH (48000*64 half4)
//   [25165824, +24576000)       VpackH            total ~47.5 MB
// ---------------------------------------------------------------------------
extern "C" void kernel_launch(void* const* d_in, const int* in_sizes, int n_in,
                              void* d_out, int out_size, void* d_ws, size_t ws_size,
                              hipStream_t stream) {
    const float* state   = (const float*)d_in[0];
    const float* feature = (const float*)d_in[1];
    const float* dist    = (const float*)d_in[2];
    const float* W1      = (const float*)d_in[3];
    const float* b1      = (const float*)d_in[4];
    const float* W2      = (const float*)d_in[5];
    const float* b2      = (const float*)d_in[6];
    const float* W3      = (const float*)d_in[7];
    const float* b3      = (const float*)d_in[8];
    const float* gate    = (const float*)d_in[9];
    const int*   src     = (const int*)d_in[10];
    const int*   dst     = (const int*)d_in[11];
    float* out = (float*)d_out;

    char* ws = (char*)d_ws;
    float*   hbuf   = (float*)(ws);
    f16*     wTh    = (f16*)(ws + 131072ULL);
    half4v*  UpackH = (half4v*)(ws + 262144ULL);
    half4v*  VpackH = (half4v*)(ws + 25165824ULL);

    hipLaunchKernelGGL(wt_prep_kernel, dim3(96), dim3(256), 0, stream,
                       W3, b3, wTh);
    hipLaunchKernelGGL(hyper_kernel, dim3((E_EDGES + 255) / 256), dim3(256), 0, stream,
                       feature, dist, W1, b1, W2, b2, src, dst, hbuf);
    hipLaunchKernelGGL(gemm_pack_mfma, dim3(ROWS / 64), dim3(256), 0, stream,
                       state, wTh, UpackH, VpackH);
    hipLaunchKernelGGL(combine_kernel, dim3(125 * BT), dim3(256), 0, stream,
                       (const float2*)UpackH, (const float2*)VpackH, hbuf, src, gate, out);
}

// Round 6
// 133.450 us; speedup vs baseline: 1.4699x; 1.0585x over previous
//
#include <hip/hip_runtime.h>
#include <hip/hip_fp16.h>
#include <math.h>

// Problem constants: N=500, DEG=16, E=8000, B=8, T=12 (BT=96), H=64, F=32
#define N_NODES 500
#define DEG     16
#define E_EDGES 8000
#define BT      96
#define H_      64
#define F_      32
#define ROWS    (BT * N_NODES)   // 48000 rows, r = bt*500 + n
#define SROW    72               // padded LDS row stride in halves (144 B = 9*16)

typedef _Float16 f16;
typedef f16   half8v  __attribute__((ext_vector_type(8)));
typedef f16   half4v  __attribute__((ext_vector_type(4)));
typedef float f32x4v  __attribute__((ext_vector_type(4)));

__device__ __forceinline__ float sigmoidf_(float x) {
    return 1.0f / (1.0f + __expf(-x));
}

// ---------------------------------------------------------------------------
// Kernel P: weight planes -> wTh[c][jj][h] fp16 (6*64*64), [col][k] layout.
// plane c: 0=A_U 1=B_U 2=C_U 3=A_V 4=B_V 5=C_V; A=W3[0].view(128,64),
// B=W3[1], C=b3; U rows (k) 0..63, V rows 64..127.
// ---------------------------------------------------------------------------
__global__ __launch_bounds__(256) void wt_prep_kernel(
        const float* __restrict__ W3, const float* __restrict__ b3,
        f16* __restrict__ wTh) {
    int i = blockIdx.x * 256 + threadIdx.x;
    if (i >= 6 * 64 * 64) return;
    int c  = i >> 12;
    int jj = (i >> 6) & 63;
    int h  = i & 63;
    const float* plane = (c % 3 == 0) ? W3 : (c % 3 == 1) ? (W3 + 8192) : b3;
    int rowbase = (c < 3) ? 0 : 64;
    wTh[i] = (f16)plane[(rowbase + h) * 64 + jj];
}

// ---------------------------------------------------------------------------
// Kernel A: per-edge hypernetwork  h = sig(sig(feat@W1+b1)@W2+b2) -> h0,h1
// ---------------------------------------------------------------------------
__global__ __launch_bounds__(256) void hyper_kernel(
        const float* __restrict__ feature, const float* __restrict__ dist,
        const float* __restrict__ W1, const float* __restrict__ b1,
        const float* __restrict__ W2, const float* __restrict__ b2,
        const int* __restrict__ src, const int* __restrict__ dst,
        float* __restrict__ hbuf) {
    __shared__ float sW1[65 * 16];
    __shared__ float sb1[16];
    __shared__ float sW2[32];
    __shared__ float sb2[2];
    for (int i = threadIdx.x; i < 65 * 16; i += blockDim.x) sW1[i] = W1[i];
    if (threadIdx.x < 16) sb1[threadIdx.x] = b1[threadIdx.x];
    if (threadIdx.x < 32) sW2[threadIdx.x] = W2[threadIdx.x];
    if (threadIdx.x < 2)  sb2[threadIdx.x] = b2[threadIdx.x];
    __syncthreads();

    int e = blockIdx.x * blockDim.x + threadIdx.x;
    if (e >= E_EDGES) return;
    int s = src[e], d = dst[e];
    float fs[F_], fd[F_];
    #pragma unroll
    for (int f = 0; f < F_; f++) fs[f] = feature[s * F_ + f];
    #pragma unroll
    for (int f = 0; f < F_; f++) fd[f] = feature[d * F_ + f];
    float dv = dist[e];

    float h1v[16];
    #pragma unroll
    for (int m = 0; m < 16; m++) {
        float acc = sb1[m] + dv * sW1[64 * 16 + m];
        #pragma unroll
        for (int f = 0; f < F_; f++) acc += fs[f] * sW1[f * 16 + m];
        #pragma unroll
        for (int f = 0; f < F_; f++) acc += fd[f] * sW1[(F_ + f) * 16 + m];
        h1v[m] = sigmoidf_(acc);
    }
    float o0 = sb2[0], o1 = sb2[1];
    #pragma unroll
    for (int m = 0; m < 16; m++) {
        o0 += h1v[m] * sW2[m * 2 + 0];
        o1 += h1v[m] * sW2[m * 2 + 1];
    }
    hbuf[e * 2 + 0] = sigmoidf_(o0);
    hbuf[e * 2 + 1] = sigmoidf_(o1);
}

// ---------------------------------------------------------------------------
// Kernel B (MFMA): flat GEMM [48000,64] @ [64,384] via mfma_f32_16x16x32_f16.
// Block = 256 thr = 4 waves, 64 rows/block (750 blocks). Unchanged from R5
// (delivered 196->141 us; not visible in top-5, don't churn blind).
// ---------------------------------------------------------------------------
__global__ __launch_bounds__(256) void gemm_pack_mfma(
        const float* __restrict__ state,
        const f16* __restrict__ wTh,
        half4v* __restrict__ UpackH, half4v* __restrict__ VpackH) {
    __shared__ __align__(16) f16 sW[384 * SROW];   // 55.3 KB
    __shared__ __align__(16) f16 sS[64 * SROW];    //  9.2 KB
    int tid = threadIdx.x;
    int r0  = blockIdx.x * 64;

    // stage W: 384 rows x 64 halves (8 x 16B chunks per row)
    #pragma unroll
    for (int i = 0; i < 12; i++) {
        int idx = tid + 256 * i;           // 3072 chunks
        int cc = idx >> 3, p = idx & 7;
        *(float4*)&sW[cc * SROW + p * 8] = ((const float4*)wTh)[idx];
    }
    // stage S: 64 rows x 64 fp32 -> fp16
    #pragma unroll
    for (int i = 0; i < 4; i++) {
        int f4 = tid + 256 * i;            // 1024 float4
        int row = f4 >> 4, p = f4 & 15;
        float4 v = ((const float4*)state)[(size_t)(r0 + row) * 16 + p];
        half4v hv = { (f16)v.x, (f16)v.y, (f16)v.z, (f16)v.w };
        *(half4v*)&sS[row * SROW + p * 4] = hv;
    }
    __syncthreads();

    int wv   = tid >> 6;
    int lane = tid & 63;
    int col  = lane & 15;
    int quad = lane >> 4;
    int m0   = wv * 16;

    // A fragments (shared across all column tiles): k = kc*32 + quad*8 + j
    half8v a0 = *(const half8v*)&sS[(m0 + col) * SROW + quad * 8];
    half8v a1 = *(const half8v*)&sS[(m0 + col) * SROW + 32 + quad * 8];

    #pragma unroll
    for (int q = 0; q < 4; q++) {
        f32x4v acc[6];
        #pragma unroll
        for (int pl = 0; pl < 6; pl++) {
            int cc0 = pl * 64 + q * 16;
            half8v b0 = *(const half8v*)&sW[(cc0 + col) * SROW + quad * 8];
            half8v b1 = *(const half8v*)&sW[(cc0 + col) * SROW + 32 + quad * 8];
            f32x4v a = {0.0f, 0.0f, 0.0f, 0.0f};
            a = __builtin_amdgcn_mfma_f32_16x16x32_f16(a0, b0, a, 0, 0, 0);
            a = __builtin_amdgcn_mfma_f32_16x16x32_f16(a1, b1, a, 0, 0, 0);
            acc[pl] = a;
        }
        f16 sv[4];
        #pragma unroll
        for (int r = 0; r < 4; r++)
            sv[r] = sS[(m0 + quad * 4 + r) * SROW + q * 16 + col];
        #pragma unroll
        for (int r = 0; r < 4; r++) {
            size_t row = (size_t)(r0 + m0 + quad * 4 + r);
            int jj = q * 16 + col;
            half4v up = { (f16)acc[0][r], (f16)acc[1][r], (f16)acc[2][r], sv[r] };
            half4v vp = { (f16)acc[3][r], (f16)acc[4][r], (f16)acc[5][r], (f16)0.0f };
            UpackH[row * H_ + jj] = up;
            VpackH[row * H_ + jj] = vp;
        }
    }
}

// ---------------------------------------------------------------------------
// Kernel C (v3): segment softmax, XCD-pinned bt-slice blocking.
// Grid = 8 * 756: xcd = blockIdx&7, j = blockIdx>>3, g = j%63 (8-node group),
// btslot = j/63 (0..11), bt = xcd + 8*btslot. Under round-robin block->XCD
// dispatch, all blocks resident on an XCD share ONE bt-slice -> per-XCD
// gather working set = 500*64*8B = 256 KB, truly L2-resident (R5's layout
// spanned ~17 slices x 8 XCDs -> 4+ MB/XCD -> gather served from L3,
// ~40 us). Each thread handles 2 adjacent jj -> 16B float4 gathers.
// 256 thr = 4 waves; lane: p = lane>>5 (node pair half), jp = lane&31
// (jj pair); node n = g*8 + wave*2 + p. Single-pass softmax (alpha bounded,
// shift-invariant).
// ---------------------------------------------------------------------------
__global__ __launch_bounds__(256) void combine_kernel(
        const float4* __restrict__ Upack4,   // 2 half4 per float4
        const float4* __restrict__ Vpack4,
        const float* __restrict__ hbuf, const int* __restrict__ src,
        const float* __restrict__ gate,
        float2* __restrict__ out2) {
    int xcd    = blockIdx.x & 7;
    int j      = blockIdx.x >> 3;
    int g      = j % 63;
    int btslot = j / 63;
    int bt     = xcd + 8 * btslot;

    int tid  = threadIdx.x;
    int wave = tid >> 6;
    int lane = tid & 63;
    int p    = lane >> 5;
    int jp   = lane & 31;
    int nl   = wave * 2 + p;       // local node 0..7
    int n    = g * 8 + nl;
    int n0   = g * 8;

    __shared__ int   s_src[128];
    __shared__ float s_h0[128], s_h1[128];
    if (tid < 128) {
        int e = n0 * DEG + tid;
        if (e < E_EDGES) {
            s_src[tid] = src[e];
            s_h0[tid]  = hbuf[e * 2 + 0];
            s_h1[tid]  = hbuf[e * 2 + 1];
        } else {
            s_src[tid] = 0; s_h0[tid] = 0.0f; s_h1[tid] = 0.0f;
        }
    }
    __syncthreads();

    if (n >= N_NODES) return;

    float sg = sigmoidf_(gate[0]);

    // V for (bt, n, jj0=2*jp, jj1=2*jp+1): one float4 = 2 half4 {A,B,C,S}
    int vidx = (bt * N_NODES + n) * 32 + jp;
    float4 vraw = Vpack4[vidx];
    float2 vx = __half22float2(*(const __half2*)&vraw.x);  // vA0, vB0
    float2 vy = __half22float2(*(const __half2*)&vraw.y);  // vC0, -
    float2 vz = __half22float2(*(const __half2*)&vraw.z);  // vA1, vB1
    float2 vw = __half22float2(*(const __half2*)&vraw.w);  // vC1, -
    float vA0 = vx.x, vB0 = vx.y, vC0 = vy.x;
    float vA1 = vz.x, vB1 = vz.y, vC1 = vw.x;

    int ubase = bt * (N_NODES * 32);   // float4 index of this bt-slice
    float l0 = 0.0f, num0 = 0.0f, l1 = 0.0f, num1 = 0.0f;
    #pragma unroll
    for (int e = 0; e < DEG; e++) {
        int ed = nl * DEG + e;
        int se = s_src[ed];
        float h0 = s_h0[ed], h1 = s_h1[ed];
        float4 u = Upack4[ubase + se * 32 + jp];
        float2 ux = __half22float2(*(const __half2*)&u.x);  // uA0, uB0
        float2 uy = __half22float2(*(const __half2*)&u.y);  // uC0, uS0
        float2 uz = __half22float2(*(const __half2*)&u.z);  // uA1, uB1
        float2 uw = __half22float2(*(const __half2*)&u.w);  // uC1, uS1
        float a0 = h0 * (ux.x + vA0) + h1 * (ux.y + vB0) + (uy.x + vC0);
        float a1 = h0 * (uz.x + vA1) + h1 * (uz.y + vB1) + (uw.x + vC1);
        a0 = (a0 > 0.0f) ? a0 : 0.01f * a0;    // leaky_relu 0.01
        a1 = (a1 > 0.0f) ? a1 : 0.01f * a1;
        float p0 = __expf(a0);
        float p1 = __expf(a1);
        l0 += p0;  num0 += p0 * uy.y;
        l1 += p1;  num1 += p1 * uw.y;
    }
    float2 r;
    r.x = fmaxf(num0 / l0, 0.0f) * sg;
    r.y = fmaxf(num1 / l1, 0.0f) * sg;
    out2[(bt * N_NODES + n) * 32 + jp] = r;    // [bt][n][jj] == [B,T,N,H]
}

// ---------------------------------------------------------------------------
// Workspace layout (bytes):
//   [0, 64000)                  hbuf   (E*2 floats)
//   [131072, +49152)            wTh    (6*64*64 fp16)
//   [262144, +24576000)         UpackH (48000*64 half4)
//   [25165824, +24576000)       VpackH            total ~47.5 MB
// ---------------------------------------------------------------------------
extern "C" void kernel_launch(void* const* d_in, const int* in_sizes, int n_in,
                              void* d_out, int out_size, void* d_ws, size_t ws_size,
                              hipStream_t stream) {
    const float* state   = (const float*)d_in[0];
    const float* feature = (const float*)d_in[1];
    const float* dist    = (const float*)d_in[2];
    const float* W1      = (const float*)d_in[3];
    const float* b1      = (const float*)d_in[4];
    const float* W2      = (const float*)d_in[5];
    const float* b2      = (const float*)d_in[6];
    const float* W3      = (const float*)d_in[7];
    const float* b3      = (const float*)d_in[8];
    const float* gate    = (const float*)d_in[9];
    const int*   src     = (const int*)d_in[10];
    const int*   dst     = (const int*)d_in[11];
    float* out = (float*)d_out;

    char* ws = (char*)d_ws;
    float*   hbuf   = (float*)(ws);
    f16*     wTh    = (f16*)(ws + 131072ULL);
    half4v*  UpackH = (half4v*)(ws + 262144ULL);
    half4v*  VpackH = (half4v*)(ws + 25165824ULL);

    hipLaunchKernelGGL(wt_prep_kernel, dim3(96), dim3(256), 0, stream,
                       W3, b3, wTh);
    hipLaunchKernelGGL(hyper_kernel, dim3((E_EDGES + 255) / 256), dim3(256), 0, stream,
                       feature, dist, W1, b1, W2, b2, src, dst, hbuf);
    hipLaunchKernelGGL(gemm_pack_mfma, dim3(ROWS / 64), dim3(256), 0, stream,
                       state, wTh, UpackH, VpackH);
    hipLaunchKernelGGL(combine_kernel, dim3(8 * 756), dim3(256), 0, stream,
                       (const float4*)UpackH, (const float4*)VpackH, hbuf, src, gate,
                       (float2*)out);
}